// Round 8
// baseline (371.924 us; speedup 1.0000x reference)
//
#include <hip/hip_runtime.h>
#include <hip/hip_bf16.h>
#include <stdint.h>

using short8 = __attribute__((ext_vector_type(8))) short;
using f32x4  = __attribute__((ext_vector_type(4))) float;

#define NBITS 3
#define NHEADS 8
#define BATCH 8192
#define DFEAT 512
#define DBASE 1024
#define DHH   1024
#define DOUT  512
#define XCOLS (NBITS + DFEAT)   // 515

static __device__ __forceinline__ unsigned short f2bf(float f) {
    union { float f; unsigned u; } v; v.f = f;
    unsigned r = v.u + 0x7FFFu + ((v.u >> 16) & 1u);   // RNE
    return (unsigned short)(r >> 16);
}

// ---------------- bucket rows by head ----------------
__global__ void k_bucket(const float* __restrict__ x, int* __restrict__ cnt,
                         int* __restrict__ rows) {
    int r = blockIdx.x * 256 + threadIdx.x;
    if (r >= BATCH) return;
    const float* xr = x + (size_t)r * XCOLS;
    int h = (xr[0] > 0.5f ? 1 : 0) | (xr[1] > 0.5f ? 2 : 0) | (xr[2] > 0.5f ? 4 : 0);
    int slot = atomicAdd(cnt + h, 1);
    rows[h * BATCH + slot] = r;
}

// ---------------- feat fp32 -> bf16 [8192][512] ----------------
__global__ void k_feat(const float* __restrict__ x, unsigned short* __restrict__ feat) {
    int t = blockIdx.x * 256 + threadIdx.x;
    int row = t >> 6, c8 = (t & 63) << 3;
    const float* src = x + (size_t)row * XCOLS + NBITS + c8;
    short8 v;
#pragma unroll
    for (int i = 0; i < 8; ++i) v[i] = (short)f2bf(src[i]);
    *(short8*)(feat + (size_t)row * DFEAT + c8) = v;
}

// ---------------- W[b][K][N] fp32 -> WT[b][N][K] bf16 ----------------
__global__ void k_transpose(const float* __restrict__ W, unsigned short* __restrict__ WT,
                            int K, int N) {
    __shared__ float tile[32][33];
    int b  = blockIdx.z;
    int n0 = blockIdx.x << 5, k0 = blockIdx.y << 5;
    int tx = threadIdx.x & 31, ty = threadIdx.x >> 5;
    const float* Wb = W + (size_t)b * K * N;
    unsigned short* WTb = WT + (size_t)b * K * N;
#pragma unroll
    for (int j = 0; j < 32; j += 8)
        tile[ty + j][tx] = Wb[(size_t)(k0 + ty + j) * N + n0 + tx];
    __syncthreads();
#pragma unroll
    for (int j = 0; j < 32; j += 8)
        WTb[(size_t)(n0 + ty + j) * K + k0 + tx] = f2bf(tile[tx][ty + j]);
}

// ========= GEMM1: 64x256 tile, A(feat) LDS-chunked, B direct-load, nt-INNERMOST bids =========
__global__ __launch_bounds__(256, 2)
void k_gemm1(const unsigned short* __restrict__ A,        // feat [8192][512]
             const unsigned short* __restrict__ BT,       // WbT  [1024][512]
             const float* __restrict__ bias,
             unsigned short* __restrict__ C) {            // base [8192][1024]
    const int bid = blockIdx.x;
    const int nt  = bid & 3;            // nt innermost: A-tile mates temporally adjacent -> L3 hit
    const int mt  = bid >> 2;
    const int m0 = mt * 64;
    const int n0 = nt * 256;

    __shared__ __align__(16) char lds[2 * 32768];

    const int t    = threadIdx.x;
    const int w    = t >> 6;
    const int lane = t & 63;
    const int ln = lane & 15, lq = lane >> 4;
    const int r7 = ln & 7;

    const unsigned short* gsrc[8];
#pragma unroll
    for (int i = 0; i < 8; ++i) {
        int r  = i * 8 + (t >> 5);
        int lg = (t & 31) ^ (r & 7);
        gsrc[i] = A + (size_t)(m0 + r) * DFEAT + lg * 8;
    }
    const unsigned short* gb[4];
#pragma unroll
    for (int n = 0; n < 4; ++n) {
        int col = n0 + w * 64 + n * 16 + ln;
        gb[n] = BT + (size_t)col * DFEAT + lq * 8;
    }
    const int dstw = w * 1024;

#define STAGEQ(cq_, d_)                                                                    \
    { _Pragma("unroll") for (int i = 0; i < 8; ++i)                                        \
        __builtin_amdgcn_global_load_lds(                                                  \
            (const __attribute__((address_space(1))) void*)(gsrc[i] + (cq_) * 256),        \
            (__attribute__((address_space(3))) void*)(lds + (d_) * 32768 + i * 4096 + dstw), \
            16, 0, 0); }

    f32x4 acc[4][4] = {};
    STAGEQ(0, 0);
    __syncthreads();

#pragma unroll 1
    for (int cq = 0; cq < 2; ++cq) {                 // K=512 -> 2 chunks of 256
        const int d = cq & 1;
        if (cq == 0) STAGEQ(1, 1);
        const char* cA = lds + d * 32768;
#pragma unroll
        for (int ks = 0; ks < 8; ++ks) {
            short8 af[4], bf[4];
#pragma unroll
            for (int m = 0; m < 4; ++m) {
                int row  = m * 16 + ln;
                int phys = ((ks * 4) | lq) ^ r7;
                af[m] = *(const short8*)(cA + row * 512 + phys * 16);
            }
#pragma unroll
            for (int n = 0; n < 4; ++n)
                bf[n] = *(const short8*)(gb[n] + cq * 256 + ks * 32);
#pragma unroll
            for (int m = 0; m < 4; ++m)
#pragma unroll
                for (int n = 0; n < 4; ++n)
                    acc[m][n] = __builtin_amdgcn_mfma_f32_16x16x32_bf16(af[m], bf[n], acc[m][n], 0, 0, 0);
        }
        __syncthreads();
    }
#undef STAGEQ

#pragma unroll
    for (int n = 0; n < 4; ++n) {
        int col = n0 + w * 64 + n * 16 + ln;
        float bv = bias[col];
#pragma unroll
        for (int m = 0; m < 4; ++m)
#pragma unroll
            for (int j = 0; j < 4; ++j) {
                int row = m0 + m * 16 + lq * 4 + j;
                float v = fmaxf(acc[m][n][j] + bv, 0.0f);
                C[(size_t)row * DBASE + col] = f2bf(v);
            }
    }
}

// ========= FUSED GEMM2+GEMM3: block = (head, 32 gathered rows); h kept in LDS =========
// H = relu(A[32][1024] @ Wh1T[head]^T + bh1);  out = H @ Wh2T[head]^T + bh2  (fp32 scatter)
// A staged ONCE (64 KB, chunk-XOR swizzle); weights read direct global->VGPR (L2/L3);
// only TWO barriers per block.  Grid 8 heads x 128 mt; empty tiles exit early.
__global__ __launch_bounds__(512, 1)
void k_fused23(const unsigned short* __restrict__ base,   // [8192][1024] bf16
               const unsigned short* __restrict__ Wh1T,   // [8][1024][1024] bf16 [e][d]
               const float* __restrict__ bh1,             // [8][1024]
               const unsigned short* __restrict__ Wh2T,   // [8][512][1024] bf16 [o][e]
               const float* __restrict__ bh2,             // [8][512]
               float* __restrict__ out,                   // [8192][512] fp32
               const int* __restrict__ rowsAll, const int* __restrict__ cntAll) {
    const int bid  = blockIdx.x;
    const int head = bid >> 7;
    const int mt   = bid & 127;
    const int M  = cntAll[head];
    const int m0 = mt * 32;
    if (m0 >= M) return;
    const int* rows = rowsAll + head * BATCH + m0;
    const int nrows = (M - m0) < 32 ? (M - m0) : 32;

    __shared__ __align__(16) char ldsA[65536];   // A [32][1024] bf16, chunk-XOR swz
    __shared__ __align__(16) char ldsH[65536];   // H [32][1024] bf16, chunk-XOR swz

    const int t = threadIdx.x, w = t >> 6, lane = t & 63;
    const int ln = lane & 15, lq = lane >> 4;

    // ---- stage A once: 4096 16B-chunks; chunk id = i*512 + t; row = id>>7, phys = id&127 ----
#pragma unroll
    for (int i = 0; i < 8; ++i) {
        int id   = i * 512 + t;
        int r    = id >> 7;
        int phys = id & 127;
        int lg   = phys ^ (r & 7);
        int rr   = r < nrows ? r : nrows - 1;
        const unsigned short* src = base + (size_t)rows[rr] * DBASE + lg * 8;
        __builtin_amdgcn_global_load_lds(
            (const __attribute__((address_space(1))) void*)src,
            (__attribute__((address_space(3))) void*)(ldsA + i * 8192 + w * 1024),
            16, 0, 0);
    }
    asm volatile("s_waitcnt vmcnt(0)" ::: "memory");
    __builtin_amdgcn_s_barrier();

    // ---- GEMM2: 4 slices of 256 cols; wave owns 32-col band per slice ----
    const unsigned short* W1 = Wh1T + (size_t)head * DHH * DBASE;
    const float* b1 = bh1 + head * DHH;
#pragma unroll 1
    for (int s = 0; s < 4; ++s) {
        const int cbase = s * 256 + w * 32;
        f32x4 acc[2][2];
#pragma unroll
        for (int nf = 0; nf < 2; ++nf) {
            float bv = b1[cbase + nf * 16 + ln];
#pragma unroll
            for (int m = 0; m < 2; ++m) acc[m][nf] = (f32x4){bv, bv, bv, bv};
        }
        const unsigned short* w1p[2];
#pragma unroll
        for (int nf = 0; nf < 2; ++nf)
            w1p[nf] = W1 + (size_t)(cbase + nf * 16 + ln) * DBASE + lq * 8;
#pragma unroll 4
        for (int ks = 0; ks < 32; ++ks) {
            int phys = ((ks * 4 + lq) ^ (ln & 7)) * 16;
            short8 a0 = *(const short8*)(ldsA + ln * 2048 + phys);
            short8 a1 = *(const short8*)(ldsA + (16 + ln) * 2048 + phys);
            short8 b0 = *(const short8*)(w1p[0] + ks * 32);
            short8 bv1 = *(const short8*)(w1p[1] + ks * 32);
            acc[0][0] = __builtin_amdgcn_mfma_f32_16x16x32_bf16(a0, b0,  acc[0][0], 0, 0, 0);
            acc[1][0] = __builtin_amdgcn_mfma_f32_16x16x32_bf16(a1, b0,  acc[1][0], 0, 0, 0);
            acc[0][1] = __builtin_amdgcn_mfma_f32_16x16x32_bf16(a0, bv1, acc[0][1], 0, 0, 0);
            acc[1][1] = __builtin_amdgcn_mfma_f32_16x16x32_bf16(a1, bv1, acc[1][1], 0, 0, 0);
        }
        // relu -> bf16 -> LDS H (same chunk-XOR layout; col here is GEMM3's k-index)
#pragma unroll
        for (int nf = 0; nf < 2; ++nf)
#pragma unroll
            for (int m = 0; m < 2; ++m)
#pragma unroll
                for (int j = 0; j < 4; ++j) {
                    int row = m * 16 + lq * 4 + j;
                    int col = cbase + nf * 16 + ln;
                    float v = fmaxf(acc[m][nf][j], 0.0f);
                    int phys = (col >> 3) ^ (row & 7);
                    *(unsigned short*)(ldsH + row * 2048 + phys * 16 + (col & 7) * 2) = f2bf(v);
                }
    }
    __syncthreads();                                  // all H visible

    // ---- GEMM3: out[32][512]; wave owns 64-col band; K=1024 from ldsH ----
    const unsigned short* W2 = Wh2T + (size_t)head * DOUT * DHH;
    const float* b2 = bh2 + head * DOUT;
    f32x4 acc3[2][4];
    const unsigned short* w2p[4];
#pragma unroll
    for (int nf = 0; nf < 4; ++nf) {
        int col = w * 64 + nf * 16 + ln;
        float bv = b2[col];
        acc3[0][nf] = (f32x4){bv, bv, bv, bv};
        acc3[1][nf] = (f32x4){bv, bv, bv, bv};
        w2p[nf] = W2 + (size_t)col * DHH + lq * 8;
    }
#pragma unroll 4
    for (int ks = 0; ks < 32; ++ks) {
        int phys = ((ks * 4 + lq) ^ (ln & 7)) * 16;
        short8 a0 = *(const short8*)(ldsH + ln * 2048 + phys);
        short8 a1 = *(const short8*)(ldsH + (16 + ln) * 2048 + phys);
        short8 bf[4];
#pragma unroll
        for (int nf = 0; nf < 4; ++nf)
            bf[nf] = *(const short8*)(w2p[nf] + ks * 32);
#pragma unroll
        for (int nf = 0; nf < 4; ++nf) {
            acc3[0][nf] = __builtin_amdgcn_mfma_f32_16x16x32_bf16(a0, bf[nf], acc3[0][nf], 0, 0, 0);
            acc3[1][nf] = __builtin_amdgcn_mfma_f32_16x16x32_bf16(a1, bf[nf], acc3[1][nf], 0, 0, 0);
        }
    }
    // ---- epilogue: scatter fp32 ----
#pragma unroll
    for (int nf = 0; nf < 4; ++nf) {
        int col = w * 64 + nf * 16 + ln;
#pragma unroll
        for (int m = 0; m < 2; ++m)
#pragma unroll
            for (int j = 0; j < 4; ++j) {
                int rt = m * 16 + lq * 4 + j;
                if (rt < nrows)
                    out[(size_t)rows[rt] * DOUT + col] = acc3[m][nf][j];
            }
    }
}

extern "C" void kernel_launch(void* const* d_in, const int* in_sizes, int n_in,
                              void* d_out, int out_size, void* d_ws, size_t ws_size,
                              hipStream_t stream) {
    const float* x   = (const float*)d_in[0];
    const float* Wb  = (const float*)d_in[1];
    const float* bb  = (const float*)d_in[2];
    const float* Wh1 = (const float*)d_in[3];
    const float* bh1 = (const float*)d_in[4];
    const float* Wh2 = (const float*)d_in[5];
    const float* bh2 = (const float*)d_in[6];

    char* ws = (char*)d_ws;
    unsigned short* feat = (unsigned short*)(ws);                          //  8 MB
    unsigned short* WbT  = (unsigned short*)(ws + (8ull  << 20));          //  1 MB
    unsigned short* Wh1T = (unsigned short*)(ws + (9ull  << 20));          // 16 MB
    unsigned short* Wh2T = (unsigned short*)(ws + (25ull << 20));          //  8 MB
    unsigned short* base = (unsigned short*)(ws + (33ull << 20));          // 16 MB
    int* rows            = (int*)(ws + (49ull << 20));                     // 256 KB
    int* cnt             = (int*)(ws + (49ull << 20) + (256ull << 10));    // 32 B

    hipMemsetAsync(cnt, 0, NHEADS * sizeof(int), stream);
    k_bucket<<<BATCH / 256, 256, 0, stream>>>(x, cnt, rows);
    k_feat<<<(BATCH * 64) / 256, 256, 0, stream>>>(x, feat);
    k_transpose<<<dim3(DBASE / 32, DFEAT / 32, 1), 256, 0, stream>>>(Wb, WbT, DFEAT, DBASE);
    k_transpose<<<dim3(DHH / 32, DBASE / 32, NHEADS), 256, 0, stream>>>(Wh1, Wh1T, DBASE, DHH);
    k_transpose<<<dim3(DOUT / 32, DHH / 32, NHEADS), 256, 0, stream>>>(Wh2, Wh2T, DHH, DOUT);

    // GEMM1: base = relu(feat @ Wb + bb)   M=8192 K=512 N=1024 ; 128 mt x 4 nt, nt innermost
    k_gemm1<<<512, 256, 0, stream>>>(feat, WbT, bb, base);
    // FUSED GEMM2+GEMM3: grid 8 heads x 128 m-tiles (32 rows each); empties exit
    k_fused23<<<1024, 512, 0, stream>>>(base, Wh1T, bh1, Wh2T, bh2,
                                        (float*)d_out, rows, cnt);
}

// Round 9
// 345.188 us; speedup vs baseline: 1.0775x; 1.0775x over previous
//
#include <hip/hip_runtime.h>
#include <hip/hip_bf16.h>
#include <stdint.h>

using short8 = __attribute__((ext_vector_type(8))) short;
using f32x4  = __attribute__((ext_vector_type(4))) float;

#define NBITS 3
#define NHEADS 8
#define BATCH 8192
#define DFEAT 512
#define DBASE 1024
#define DHH   1024
#define DOUT  512
#define XCOLS (NBITS + DFEAT)   // 515

static __device__ __forceinline__ unsigned short f2bf(float f) {
    union { float f; unsigned u; } v; v.f = f;
    unsigned r = v.u + 0x7FFFu + ((v.u >> 16) & 1u);   // RNE
    return (unsigned short)(r >> 16);
}

// ================= CALIBRATION PROBES (machine-scale diagnosis) =================
// probe_mfma: 256 blocks x 8 waves x 1024 MFMA each, no memory in loop.
//   256 CUs @2.4GHz -> ~17 us;  32-CU partition -> ~132 us (visible in top-5).
__global__ __launch_bounds__(512) void k_probe_mfma(const unsigned short* __restrict__ src,
                                                    float* __restrict__ sink) {
    short8 a = *(const short8*)(src);       // opaque init (no const-fold)
    f32x4 c[8] = {};
#pragma unroll 16
    for (int i = 0; i < 128; ++i) {
#pragma unroll
        for (int j = 0; j < 8; ++j)
            c[j] = __builtin_amdgcn_mfma_f32_16x16x32_bf16(a, a, c[j], 0, 0, 0);
    }
    float s = 0.f;
#pragma unroll
    for (int j = 0; j < 8; ++j) s += c[j][0];
    sink[blockIdx.x * 512 + threadIdx.x] = s;
}

// probe_hbm: coalesced read of 32 MB (Wh1 fp32).  6.3 TB/s -> ~5 us; ~750 GB/s -> ~43 us.
__global__ __launch_bounds__(256) void k_probe_hbm(const float* __restrict__ src,
                                                   float* __restrict__ sink, int n4) {
    const float4* s4 = (const float4*)src;
    int stride = gridDim.x * 256;
    float acc = 0.f;
    for (int i = blockIdx.x * 256 + threadIdx.x; i < n4; i += stride) {
        float4 v = s4[i];
        acc += v.x + v.y + v.z + v.w;
    }
    sink[blockIdx.x * 256 + threadIdx.x] = acc;
}

// ---------------- bucket rows by head ----------------
__global__ void k_bucket(const float* __restrict__ x, int* __restrict__ cnt,
                         int* __restrict__ rows) {
    int r = blockIdx.x * 256 + threadIdx.x;
    if (r >= BATCH) return;
    const float* xr = x + (size_t)r * XCOLS;
    int h = (xr[0] > 0.5f ? 1 : 0) | (xr[1] > 0.5f ? 2 : 0) | (xr[2] > 0.5f ? 4 : 0);
    int slot = atomicAdd(cnt + h, 1);
    rows[h * BATCH + slot] = r;
}

// ---------------- feat fp32 -> bf16 [8192][512] ----------------
__global__ void k_feat(const float* __restrict__ x, unsigned short* __restrict__ feat) {
    int t = blockIdx.x * 256 + threadIdx.x;
    int row = t >> 6, c8 = (t & 63) << 3;
    const float* src = x + (size_t)row * XCOLS + NBITS + c8;
    short8 v;
#pragma unroll
    for (int i = 0; i < 8; ++i) v[i] = (short)f2bf(src[i]);
    *(short8*)(feat + (size_t)row * DFEAT + c8) = v;
}

// ---------------- W[b][K][N] fp32 -> WT[b][N][K] bf16 ----------------
__global__ void k_transpose(const float* __restrict__ W, unsigned short* __restrict__ WT,
                            int K, int N) {
    __shared__ float tile[32][33];
    int b  = blockIdx.z;
    int n0 = blockIdx.x << 5, k0 = blockIdx.y << 5;
    int tx = threadIdx.x & 31, ty = threadIdx.x >> 5;
    const float* Wb = W + (size_t)b * K * N;
    unsigned short* WTb = WT + (size_t)b * K * N;
#pragma unroll
    for (int j = 0; j < 32; j += 8)
        tile[ty + j][tx] = Wb[(size_t)(k0 + ty + j) * N + n0 + tx];
    __syncthreads();
#pragma unroll
    for (int j = 0; j < 32; j += 8)
        WTb[(size_t)(n0 + ty + j) * K + k0 + tx] = f2bf(tile[tx][ty + j]);
}

// ============ 128x256 MFMA GEMM (R4 structure, carried verbatim as A/B control) ============
template<bool GATHER, bool RELU, bool OUTBF16>
__global__ __launch_bounds__(512, 1)
void k_gemm2(const unsigned short* __restrict__ A, int lda, int K,
             const unsigned short* __restrict__ BT,
             const float* __restrict__ bias,
             void* __restrict__ C, int ldc,
             const int* __restrict__ rowsAll, const int* __restrict__ cntAll,
             int Nfull, int nshift) {
    const int bid  = blockIdx.x;
    const int mt   = bid & 63;
    const int nt   = (bid >> 6) & ((1 << nshift) - 1);
    const int head = GATHER ? (bid >> (6 + nshift)) : 0;
    const int m0 = mt * 128;
    const int n0 = nt * 256;
    int M = BATCH;
    const int* rows = nullptr;
    if (GATHER) {
        M = cntAll[head];
        if (m0 >= M) return;
        rows = rowsAll + head * BATCH;
    }
    const unsigned short* BTh = BT + (size_t)head * Nfull * K;
    const float* biash = bias + (size_t)head * Nfull;

    __shared__ __align__(16) char lds[98304];
    char* ldsp = lds;

    const int t    = threadIdx.x;
    const int w    = t >> 6;
    const int lane = t & 63;
    const int wr = w >> 2, wc = w & 3;
    const int ln = lane & 15, lq = lane >> 4;

    const unsigned short* gA[2];
    {
        int rl  = t >> 3;
        int kch = (t & 7) ^ (rl & 7);
#pragma unroll
        for (int h = 0; h < 2; ++h) {
            int idx = m0 + h * 64 + rl;
            int r;
            if (GATHER) { idx = idx < M ? idx : (M - 1); r = rows[idx]; }
            else r = idx;
            gA[h] = A + (size_t)r * lda + kch * 8;
        }
    }
    const unsigned short* gB[2][2];
#pragma unroll
    for (int hb = 0; hb < 2; ++hb)
#pragma unroll
        for (int i = 0; i < 2; ++i) {
            int c   = i * 512 + t;
            int cl  = c >> 3;
            int kch = (c & 7) ^ (cl & 7);
            int ncol = n0 + hb * 128 + cl;
            gB[hb][i] = BTh + (size_t)ncol * K + kch * 8;
        }

#define STAGE_A(kt, d)                                                                     \
    { _Pragma("unroll") for (int h = 0; h < 2; ++h)                                        \
        __builtin_amdgcn_global_load_lds(                                                  \
            (const __attribute__((address_space(1))) void*)(gA[h] + (kt) * 64),            \
            (__attribute__((address_space(3))) void*)(ldsp + (d) * 16384 + h * 8192 + w * 1024), \
            16, 0, 0); }
#define STAGE_B(kt, d)                                                                     \
    { _Pragma("unroll") for (int hb = 0; hb < 2; ++hb)                                     \
      _Pragma("unroll") for (int i = 0; i < 2; ++i)                                        \
        __builtin_amdgcn_global_load_lds(                                                  \
            (const __attribute__((address_space(1))) void*)(gB[hb][i] + (kt) * 64),        \
            (__attribute__((address_space(3))) void*)(ldsp + 32768 + (d) * 32768 + hb * 16384 + i * 8192 + w * 1024), \
            16, 0, 0); }
#define LOAD_A(dst, d, ks)                                                                 \
    { _Pragma("unroll") for (int m = 0; m < 4; ++m) {                                      \
        int rA = wr * 64 + m * 16 + ln;                                                    \
        int ch = (((ks) << 2) | lq) ^ (ln & 7);                                            \
        dst[m] = *(const short8*)(ldsp + (d) * 16384 + rA * 128 + ch * 16); } }
#define LOAD_B(dst, d, ks)                                                                 \
    { _Pragma("unroll") for (int n = 0; n < 4; ++n) {                                      \
        int cB = wc * 64 + n * 16 + ln;                                                    \
        int ch = (((ks) << 2) | lq) ^ (ln & 7);                                            \
        dst[n] = *(const short8*)(ldsp + 32768 + (d) * 32768 + cB * 128 + ch * 16); } }
#define MFMA16(av, bv)                                                                     \
    { __builtin_amdgcn_s_setprio(1);                                                       \
      _Pragma("unroll") for (int m = 0; m < 4; ++m)                                        \
      _Pragma("unroll") for (int n = 0; n < 4; ++n)                                        \
        acc[m][n] = __builtin_amdgcn_mfma_f32_16x16x32_bf16(av[m], bv[n], acc[m][n], 0, 0, 0); \
      __builtin_amdgcn_s_setprio(0); }

    f32x4 acc[4][4] = {};
    short8 a0[4], b0[4], a1[4], b1[4];
    const int NT = K >> 6;

    STAGE_A(0, 0); STAGE_B(0, 0); STAGE_A(1, 1);
    __syncthreads();
    LOAD_A(a0, 0, 0); LOAD_B(b0, 0, 0);

    for (int kt = 0; kt < NT; ++kt) {
        const int d = kt & 1, o = d ^ 1;
        const int kB = (kt + 1 < NT) ? kt + 1 : NT - 1;
        const int kA = (kt + 2 < NT) ? kt + 2 : NT - 1;
        STAGE_B(kB, o);
        LOAD_A(a1, d, 1); LOAD_B(b1, d, 1);
        MFMA16(a0, b0);
        __syncthreads();
        STAGE_A(kA, d);
        LOAD_A(a0, o, 0); LOAD_B(b0, o, 0);
        MFMA16(a1, b1);
    }
#undef STAGE_A
#undef STAGE_B
#undef LOAD_A
#undef LOAD_B
#undef MFMA16

#pragma unroll
    for (int n = 0; n < 4; ++n) {
        int col = n0 + wc * 64 + n * 16 + ln;
        float bv = biash[col];
#pragma unroll
        for (int m = 0; m < 4; ++m) {
#pragma unroll
            for (int j = 0; j < 4; ++j) {
                int rt = wr * 64 + m * 16 + lq * 4 + j;
                int grow;
                if (GATHER) {
                    if (m0 + rt >= M) continue;
                    grow = rows[m0 + rt];
                } else {
                    grow = m0 + rt;
                }
                float v = acc[m][n][j] + bv;
                if (RELU) v = fmaxf(v, 0.0f);
                if (OUTBF16)
                    ((unsigned short*)C)[(size_t)grow * ldc + col] = f2bf(v);
                else
                    ((float*)C)[(size_t)grow * ldc + col] = v;
            }
        }
    }
}

extern "C" void kernel_launch(void* const* d_in, const int* in_sizes, int n_in,
                              void* d_out, int out_size, void* d_ws, size_t ws_size,
                              hipStream_t stream) {
    const float* x   = (const float*)d_in[0];
    const float* Wb  = (const float*)d_in[1];
    const float* bb  = (const float*)d_in[2];
    const float* Wh1 = (const float*)d_in[3];
    const float* bh1 = (const float*)d_in[4];
    const float* Wh2 = (const float*)d_in[5];
    const float* bh2 = (const float*)d_in[6];

    char* ws = (char*)d_ws;
    unsigned short* feat = (unsigned short*)(ws);                          //  8 MB
    unsigned short* WbT  = (unsigned short*)(ws + (8ull  << 20));          //  1 MB
    unsigned short* Wh1T = (unsigned short*)(ws + (9ull  << 20));          // 16 MB
    unsigned short* Wh2T = (unsigned short*)(ws + (25ull << 20));          //  8 MB
    unsigned short* base = (unsigned short*)(ws + (33ull << 20));          // 16 MB
    unsigned short* hbuf = (unsigned short*)(ws + (49ull << 20));          // 16 MB
    int* rows            = (int*)(ws + (65ull << 20));                     // 256 KB
    int* cnt             = (int*)(ws + (65ull << 20) + (256ull << 10));    // 32 B
    // probe sinks live inside `base` region (fully overwritten by GEMM1 afterwards)
    float* psink = (float*)(ws + (33ull << 20));                           // 512 KB
    float* hsink = (float*)(ws + (34ull << 20));                           //   2 MB

    // -------- calibration probes (run first; results read via rocprof timing only) --------
    k_probe_mfma<<<256, 512, 0, stream>>>((const unsigned short*)Wb, psink);
    k_probe_hbm<<<2048, 256, 0, stream>>>(Wh1, hsink, (8 * 1024 * 1024) / 4);

    hipMemsetAsync(cnt, 0, NHEADS * sizeof(int), stream);
    k_bucket<<<BATCH / 256, 256, 0, stream>>>(x, cnt, rows);
    k_feat<<<(BATCH * 64) / 256, 256, 0, stream>>>(x, feat);
    k_transpose<<<dim3(DBASE / 32, DFEAT / 32, 1), 256, 0, stream>>>(Wb, WbT, DFEAT, DBASE);
    k_transpose<<<dim3(DHH / 32, DBASE / 32, NHEADS), 256, 0, stream>>>(Wh1, Wh1T, DBASE, DHH);
    k_transpose<<<dim3(DOUT / 32, DHH / 32, NHEADS), 256, 0, stream>>>(Wh2, Wh2T, DHH, DOUT);

    // GEMM1: base = relu(feat @ Wb + bb)   M=8192 K=512 N=1024 ; 64 mt x 4 nt
    k_gemm2<false, true, true><<<256, 512, 0, stream>>>(
        feat, DFEAT, DFEAT, WbT, bb, base, DBASE, nullptr, nullptr, DBASE, 2);
    // GEMM2: h = relu(base @ Wh1[h] + bh1[h])  grouped, K=1024 N=1024 ; 64 mt x 4 nt x 8 heads
    k_gemm2<true, true, true><<<2048, 512, 0, stream>>>(
        base, DBASE, DBASE, Wh1T, bh1, hbuf, DHH, rows, cnt, DHH, 2);
    // GEMM3: out = h @ Wh2[h] + bh2[h]         grouped, K=1024 N=512, fp32 out ; 64 x 2 x 8
    k_gemm2<true, false, false><<<1024, 512, 0, stream>>>(
        hbuf, DHH, DHH, Wh2T, bh2, d_out, DOUT, rows, cnt, DOUT, 1);
}